// Round 7
// baseline (1480.481 us; speedup 1.0000x reference)
//
#include <hip/hip_runtime.h>
#include <math.h>

#define B_ 8192

typedef __attribute__((ext_vector_type(8))) short short8;
typedef __attribute__((ext_vector_type(4))) float f32x4;

// ---------------- persistent device buffers (rewritten every call) ----------------
// weights (hi/lo split bf16, stored as B^T row-major [N][K])
__device__ float          g_w1t[51200];                    // conv1 [l*25+q][64] fp32, /max_vec
__device__ unsigned short g_w2hi[36864],  g_w2lo[36864];   // conv2 [64][576], k'=(kx*3+ky)*64+ic
__device__ unsigned short g_fc1hi[32768], g_fc1lo[32768];  // fc1   [128][256] (k'=pos*64+oc)
__device__ unsigned short g_enchi[16384], g_enclo[16384];  // enc   [128][128]
__device__ unsigned short g_crhi[131072], g_crlo[131072];  // critic[1024][128]
__device__ unsigned short g_achi[65536],  g_aclo[65536];   // actor [512][128]
__device__ unsigned short g_qWhi[8192],   g_qWlo[8192];    // actor_W^T [16][512]
// activations (hi/lo split bf16)
__device__ unsigned short g_ACT1hi[8192*1024], g_ACT1lo[8192*1024]; // conv1 out [s][cell16*64+oc]
__device__ unsigned short g_A1hi[8192*256],  g_A1lo[8192*256];  // conv2 out [s][pos*64+oc]
__device__ unsigned short g_A2hi[8192*128],  g_A2lo[8192*128];  // fc1 out
__device__ unsigned short g_Hhi[8192*128],   g_Hlo[8192*128];   // enc out (hidden)
__device__ unsigned short g_AFhi[8192*512],  g_AFlo[8192*512];  // actor out

__device__ __forceinline__ unsigned short f2bf(float v){
    unsigned u = __builtin_bit_cast(unsigned, v);
    unsigned r = (u + 0x7fffu + ((u >> 16) & 1u)) >> 16;   // RN-even (finite inputs)
    return (unsigned short)r;
}
__device__ __forceinline__ float bf2f(unsigned short h){
    unsigned u = ((unsigned)h) << 16;
    return __builtin_bit_cast(float, u);
}
__device__ __forceinline__ void split_store(float v, unsigned short* hi, unsigned short* lo){
    unsigned short h = f2bf(v);
    *hi = h;
    *lo = f2bf(v - bf2f(h));
}

// ---------------- prep: transpose + split all weights ----------------
__global__ __launch_bounds__(256) void prep_kernel(
    const float* __restrict__ w1, const float* __restrict__ maxv,
    const float* __restrict__ w2, const float* __restrict__ fc1,
    const float* __restrict__ enc, const float* __restrict__ cr,
    const float* __restrict__ ac, const float* __restrict__ aW)
{
    int d = blockIdx.x * 256 + threadIdx.x;
    if (d < 51200){
        int oc = d & 63, r = d >> 6;
        int l = r / 25, q = r - l*25;
        g_w1t[d] = w1[oc*800 + l*25 + q] / maxv[l];
        return;
    }
    d -= 51200;
    if (d < 36864){
        int oc = d / 576, k2 = d - oc*576;
        int kxy = k2 >> 6, ic = k2 & 63;               // k' = kxy*64 + ic
        split_store(w2[oc*576 + ic*9 + kxy], &g_w2hi[d], &g_w2lo[d]);
        return;
    }
    d -= 36864;
    if (d < 32768){
        int o = d >> 8, kp = d & 255;                  // k' = pos*64+oc
        split_store(fc1[o*256 + (kp & 63)*4 + (kp >> 6)], &g_fc1hi[d], &g_fc1lo[d]);
        return;
    }
    d -= 32768;
    if (d < 16384){ split_store(enc[d], &g_enchi[d], &g_enclo[d]); return; }
    d -= 16384;
    if (d < 131072){ split_store(cr[d], &g_crhi[d], &g_crlo[d]); return; }
    d -= 131072;
    if (d < 65536){ split_store(ac[d], &g_achi[d], &g_aclo[d]); return; }
    d -= 65536;
    { int e = d >> 9, j = d & 511; split_store(aW[j*16 + e], &g_qWhi[d], &g_qWlo[d]); }
}

// ---------------- front-end: pairwise last-wins + branch-free pipelined scatter ----------
__global__ __launch_bounds__(256) void frontend_kernel(const int* __restrict__ obs,
                                                       const float* __restrict__ b1)
{
    const int b = blockIdx.x, tid = threadIdx.x;
    __shared__ int   s_obs[600];
    __shared__ int   s_cell[200];
    __shared__ float s_cval[200];
    __shared__ float part[17 * 64];          // [pos 0..15][oc]; row 16 = junk sink

    for (int k = tid; k < 600; k += 256) s_obs[k] = obs[b*600 + k];
    for (int k = tid; k < 1088; k += 256) part[k] = 0.f;
    __syncthreads();

    if (tid < 200){
        int coord = s_obs[tid*3], atr = s_obs[tid*3+1], val = s_obs[tid*3+2];
        bool valid = (coord != 255) && (atr < 32);
        int x = (coord >> 4) & 15, y = coord & 15;
        s_cell[tid] = valid ? (atr*256 + x*16 + y) : 0;   // invalid claims cell 0 (ref semantics)
        // x>=14 / y>=14 cells are never read by the 5x5/s3 VALID conv
        s_cval[tid] = (valid && x < 14 && y < 14) ? (float)val : 0.f;
    }
    __syncthreads();
    // last-wins: token t kept iff no later token claims the same cell
    if (tid < 200){
        int c = s_cell[tid];
        bool kept = true;
        #pragma unroll 4
        for (int j = tid + 1; j < 200; j++) kept &= (s_cell[j] != c);
        if (!kept) s_cval[tid] = 0.f;
    }
    __syncthreads();

    // branch-free sparse conv1 scatter into part[pos][oc]; lane = oc (stride-1, conflict-free)
    {
        const int oc = tid & 63, g = tid >> 6;
        #pragma unroll 2
        for (int k = g; k < 200; k += 4){
            float v = s_cval[k];                          // wave-uniform
            if (v != 0.f){                                // single wave-uniform skip
                int c = s_cell[k];
                int l = c >> 8, x = (c >> 4) & 15, y = c & 15;
                int x3 = x/3, rx = x - 3*x3;
                int y3 = y/3, ry = y - 3*y3;
                const float* wl = &g_w1t[l*1600 + oc];
                float wv[4]; float addv[4]; int tgt[4];
                #pragma unroll
                for (int d = 0; d < 4; d++){
                    int dx = d >> 1, dy = d & 1;
                    int ox = x3 - dx, oy = y3 - dy;
                    int wx = rx + 3*dx, wy = ry + 3*dy;
                    bool ok = ((unsigned)ox <= 3u) && ((unsigned)oy <= 3u)
                           && (wx < 5) && (wy < 5);
                    int woff = ok ? (wx*5 + wy)*64 : 0;   // clamped: always safe
                    wv[d]  = wl[woff];                    // 4 unconditional loads, batched
                    tgt[d] = ok ? (ox*4 + oy) : 16;       // junk row absorbs invalid
                    addv[d] = ok ? v : 0.f;
                }
                #pragma unroll
                for (int d = 0; d < 4; d++)
                    atomicAdd(&part[tgt[d]*64 + oc], addv[d] * wv[d]);
            }
        }
    }
    __syncthreads();

    // bias + relu, split-store compact act1 [pos][oc] (pos = x3*4+y3)
    for (int r = tid; r < 1024; r += 256){
        int oc2 = r & 63;
        float vfin = fmaxf(part[r] + b1[oc2], 0.f);
        unsigned short h = f2bf(vfin);
        g_ACT1hi[b*1024 + r] = h;
        g_ACT1lo[b*1024 + r] = f2bf(vfin - bf2f(h));
    }
}

// ---------------- conv2: im2col-on-load MFMA GEMM (M=32768, N=64, K=576) ----------------
__global__ __launch_bounds__(256) void conv2_kernel(const float* __restrict__ bias)
{
    const int r0 = blockIdx.x * 64;                      // 16 samples x 4 pos
    const int tid = threadIdx.x, wave = tid >> 6, lane = tid & 63;
    const int l15 = lane & 15, lhi = lane >> 4;

    __shared__ unsigned short sAhi[64][72];
    __shared__ unsigned short sAlo[64][72];

    f32x4 acc[4] = {{0,0,0,0},{0,0,0,0},{0,0,0,0},{0,0,0,0}};
    for (int kc = 0; kc < 9; kc++){                      // (kx,ky) chunk of 64 k's
        const int kx = kc / 3, ky = kc - 3*kx;
        __syncthreads();
        #pragma unroll
        for (int u = 0; u < 2; u++){
            int unit = tid + u*256;
            int row = unit >> 3, ch8 = (unit & 7) * 8;
            int px = (row >> 1) & 1, py = row & 1;       // pos = row&3
            int cell = (px + kx)*4 + (py + ky);
            int g = ((r0 >> 2) + (row >> 2))*1024 + cell*64 + ch8;
            *(short8*)&sAhi[row][ch8] = *(const short8*)&g_ACT1hi[g];
            *(short8*)&sAlo[row][ch8] = *(const short8*)&g_ACT1lo[g];
        }
        __syncthreads();
        #pragma unroll
        for (int ks = 0; ks < 2; ks++){
            const int kk = ks*32 + lhi*8;
            short8 ah = *(const short8*)&sAhi[wave*16 + l15][kk];
            short8 al = *(const short8*)&sAlo[wave*16 + l15][kk];
            #pragma unroll
            for (int nt = 0; nt < 4; nt++){
                const int n = nt*16 + l15;
                const short8 bh = *(const short8*)&g_w2hi[n*576 + kc*64 + kk];
                const short8 bl = *(const short8*)&g_w2lo[n*576 + kc*64 + kk];
                acc[nt] = __builtin_amdgcn_mfma_f32_16x16x32_bf16(ah, bh, acc[nt], 0, 0, 0);
                acc[nt] = __builtin_amdgcn_mfma_f32_16x16x32_bf16(al, bh, acc[nt], 0, 0, 0);
                acc[nt] = __builtin_amdgcn_mfma_f32_16x16x32_bf16(ah, bl, acc[nt], 0, 0, 0);
            }
        }
    }
    #pragma unroll
    for (int nt = 0; nt < 4; nt++){
        const int col = nt*16 + l15;
        const float bb = bias[col];
        #pragma unroll
        for (int j = 0; j < 4; j++){
            const int row = r0 + wave*16 + lhi*4 + j;
            float v = fmaxf(acc[nt][j] + bb, 0.f);
            unsigned short h = f2bf(v);
            g_A1hi[row*64 + col] = h;                    // == [s][pos*64+oc]
            g_A1lo[row*64 + col] = f2bf(v - bf2f(h));
        }
    }
}

// ---------------- generic 64x64 split-bf16 MFMA GEMM with relu+bias ----------
// LAYER: 1=fc1(K256,N128) 2=enc(K128,N128) 3=actor(K128,N512)
template<int LAYER>
__global__ __launch_bounds__(256) void gemm64_kernel(const float* __restrict__ bias)
{
    constexpr int K = (LAYER==1) ? 256 : 128;
    constexpr int N = (LAYER==3) ? 512 : 128;
    const unsigned short *Ahi, *Alo, *Bh, *Bl;
    unsigned short *Chi, *Clo;
    if constexpr (LAYER==1){ Ahi=g_A1hi; Alo=g_A1lo; Bh=g_fc1hi; Bl=g_fc1lo; Chi=g_A2hi; Clo=g_A2lo; }
    else if constexpr (LAYER==2){ Ahi=g_A2hi; Alo=g_A2lo; Bh=g_enchi; Bl=g_enclo; Chi=g_Hhi;  Clo=g_Hlo; }
    else                        { Ahi=g_Hhi;  Alo=g_Hlo;  Bh=g_achi;  Bl=g_aclo;  Chi=g_AFhi; Clo=g_AFlo; }

    const int r0 = blockIdx.x * 64, c0 = blockIdx.y * 64;
    const int tid = threadIdx.x, wave = tid >> 6, lane = tid & 63;
    const int l15 = lane & 15, lhi = lane >> 4;

    __shared__ unsigned short sAhi[64][72];
    __shared__ unsigned short sAlo[64][72];

    f32x4 acc[4] = {{0,0,0,0},{0,0,0,0},{0,0,0,0},{0,0,0,0}};
    for (int kb = 0; kb < K; kb += 64){
        __syncthreads();
        #pragma unroll
        for (int u = 0; u < 2; u++){
            int unit = tid + u*256;
            int row = unit >> 3, ch = (unit & 7) * 8;
            int g = (r0 + row)*K + kb + ch;
            *(short8*)&sAhi[row][ch] = *(const short8*)&Ahi[g];
            *(short8*)&sAlo[row][ch] = *(const short8*)&Alo[g];
        }
        __syncthreads();
        #pragma unroll
        for (int ks = 0; ks < 2; ks++){
            const int kk = ks*32 + lhi*8;
            short8 ah = *(const short8*)&sAhi[wave*16 + l15][kk];
            short8 al = *(const short8*)&sAlo[wave*16 + l15][kk];
            #pragma unroll
            for (int nt = 0; nt < 4; nt++){
                const int n = c0 + nt*16 + l15;
                const short8 bh = *(const short8*)&Bh[n*K + kb + kk];
                const short8 bl = *(const short8*)&Bl[n*K + kb + kk];
                acc[nt] = __builtin_amdgcn_mfma_f32_16x16x32_bf16(ah, bh, acc[nt], 0, 0, 0);
                acc[nt] = __builtin_amdgcn_mfma_f32_16x16x32_bf16(al, bh, acc[nt], 0, 0, 0);
                acc[nt] = __builtin_amdgcn_mfma_f32_16x16x32_bf16(ah, bl, acc[nt], 0, 0, 0);
            }
        }
    }
    #pragma unroll
    for (int nt = 0; nt < 4; nt++){
        const int col = c0 + nt*16 + l15;
        const float bb = bias[col];
        #pragma unroll
        for (int j = 0; j < 4; j++){
            const int row = r0 + wave*16 + lhi*4 + j;
            float v = fmaxf(acc[nt][j] + bb, 0.f);
            unsigned short h = f2bf(v);
            Chi[row*N + col] = h;
            Clo[row*N + col] = f2bf(v - bf2f(h));
        }
    }
}

// ---------------- critic: [16 rows] x 1024 cols, tanh + vw dot -> value ----------------
__global__ __launch_bounds__(256) void critic_kernel(const float* __restrict__ crb,
    const float* __restrict__ vw, const float* __restrict__ vb, float* __restrict__ outv)
{
    const int r0 = blockIdx.x * 16;
    const int tid = threadIdx.x, wave = tid >> 6, lane = tid & 63;
    const int l15 = lane & 15, lhi = lane >> 4;
    __shared__ unsigned short sAhi[16][136], sAlo[16][136];
    __shared__ float s_v[4][16];
    {
        int row = tid >> 4, ch = (tid & 15) * 8;
        int g = (r0 + row)*128 + ch;
        *(short8*)&sAhi[row][ch] = *(const short8*)&g_Hhi[g];
        *(short8*)&sAlo[row][ch] = *(const short8*)&g_Hlo[g];
    }
    __syncthreads();
    f32x4 acc[16];
    #pragma unroll
    for (int nt = 0; nt < 16; nt++) acc[nt] = f32x4{0,0,0,0};
    #pragma unroll
    for (int ks = 0; ks < 4; ks++){
        const int kk = ks*32 + lhi*8;
        short8 ah = *(const short8*)&sAhi[l15][kk];
        short8 al = *(const short8*)&sAlo[l15][kk];
        #pragma unroll
        for (int nt = 0; nt < 16; nt++){
            const int n = wave*256 + nt*16 + l15;
            const short8 bh = *(const short8*)&g_crhi[n*128 + kk];
            const short8 bl = *(const short8*)&g_crlo[n*128 + kk];
            acc[nt] = __builtin_amdgcn_mfma_f32_16x16x32_bf16(ah, bh, acc[nt], 0, 0, 0);
            acc[nt] = __builtin_amdgcn_mfma_f32_16x16x32_bf16(al, bh, acc[nt], 0, 0, 0);
            acc[nt] = __builtin_amdgcn_mfma_f32_16x16x32_bf16(ah, bl, acc[nt], 0, 0, 0);
        }
    }
    float vp[4] = {0.f, 0.f, 0.f, 0.f};
    #pragma unroll
    for (int nt = 0; nt < 16; nt++){
        const int col = wave*256 + nt*16 + l15;
        const float w = vw[col], bb = crb[col];
        #pragma unroll
        for (int j = 0; j < 4; j++) vp[j] += tanhf(acc[nt][j] + bb) * w;
    }
    #pragma unroll
    for (int m = 1; m < 16; m <<= 1){
        #pragma unroll
        for (int j = 0; j < 4; j++) vp[j] += __shfl_xor(vp[j], m, 64);
    }
    if (l15 == 0){
        #pragma unroll
        for (int j = 0; j < 4; j++) s_v[wave][lhi*4 + j] = vp[j];
    }
    __syncthreads();
    if (tid < 16)
        outv[r0 + tid] = s_v[0][tid] + s_v[1][tid] + s_v[2][tid] + s_v[3][tid] + vb[0];
}

// ---------------- query (AF @ actor_W^T, tanh) fused with logits ----------------
__global__ __launch_bounds__(256) void query_kernel(const float* __restrict__ emb,
    const float* __restrict__ abias, float* __restrict__ out)
{
    const int r0 = blockIdx.x * 64;
    const int tid = threadIdx.x, wave = tid >> 6, lane = tid & 63;
    const int l15 = lane & 15, lhi = lane >> 4;
    __shared__ unsigned short sAhi[64][72], sAlo[64][72];
    __shared__ float s_q[64][16];
    __shared__ float s_emb[1600];
    for (int k = tid; k < 1600; k += 256) s_emb[k] = emb[k];
    f32x4 acc = {0,0,0,0};
    for (int kb = 0; kb < 512; kb += 64){
        __syncthreads();
        #pragma unroll
        for (int u = 0; u < 2; u++){
            int unit = tid + u*256;
            int row = unit >> 3, ch = (unit & 7) * 8;
            int g = (r0 + row)*512 + kb + ch;
            *(short8*)&sAhi[row][ch] = *(const short8*)&g_AFhi[g];
            *(short8*)&sAlo[row][ch] = *(const short8*)&g_AFlo[g];
        }
        __syncthreads();
        #pragma unroll
        for (int ks = 0; ks < 2; ks++){
            const int kk = ks*32 + lhi*8;
            short8 ah = *(const short8*)&sAhi[wave*16 + l15][kk];
            short8 al = *(const short8*)&sAlo[wave*16 + l15][kk];
            const short8 bh = *(const short8*)&g_qWhi[l15*512 + kb + kk];
            const short8 bl = *(const short8*)&g_qWlo[l15*512 + kb + kk];
            acc = __builtin_amdgcn_mfma_f32_16x16x32_bf16(ah, bh, acc, 0, 0, 0);
            acc = __builtin_amdgcn_mfma_f32_16x16x32_bf16(al, bh, acc, 0, 0, 0);
            acc = __builtin_amdgcn_mfma_f32_16x16x32_bf16(ah, bl, acc, 0, 0, 0);
        }
    }
    #pragma unroll
    for (int j = 0; j < 4; j++)
        s_q[wave*16 + lhi*4 + j][l15] = tanhf(acc[j]);
    __syncthreads();
    for (int i = tid; i < 6400; i += 256){
        int row = i / 100, a = i - row*100;
        float s = abias[0];
        #pragma unroll
        for (int e = 0; e < 16; e++) s += s_q[row][e] * s_emb[a*16 + e];
        out[(r0 + row)*100 + a] = s;
    }
}

// ---------------- launch ----------------
extern "C" void kernel_launch(void* const* d_in, const int* in_sizes, int n_in,
                              void* d_out, int out_size, void* d_ws, size_t ws_size,
                              hipStream_t stream) {
    const int*   obs   = (const int*)  d_in[0];
    const float* maxv  = (const float*)d_in[1];
    const float* w1    = (const float*)d_in[2];
    const float* b1    = (const float*)d_in[3];
    const float* w2    = (const float*)d_in[4];
    const float* b2    = (const float*)d_in[5];
    const float* fc1w  = (const float*)d_in[6];
    const float* fc1b  = (const float*)d_in[7];
    const float* encw  = (const float*)d_in[8];
    const float* encb  = (const float*)d_in[9];
    const float* crw   = (const float*)d_in[10];
    const float* crb   = (const float*)d_in[11];
    const float* vw    = (const float*)d_in[12];
    const float* vb    = (const float*)d_in[13];
    const float* acw   = (const float*)d_in[14];
    const float* acb   = (const float*)d_in[15];
    const float* emb   = (const float*)d_in[16];
    const float* aW    = (const float*)d_in[17];
    const float* abias = (const float*)d_in[18];
    float* out = (float*)d_out;

    prep_kernel<<<1336, 256, 0, stream>>>(w1, maxv, w2, fc1w, encw, crw, acw, aW);
    frontend_kernel<<<B_, 256, 0, stream>>>(obs, b1);
    conv2_kernel<<<512, 256, 0, stream>>>(b2);
    gemm64_kernel<1><<<dim3(128, 2), 256, 0, stream>>>(fc1b);  // fc1
    gemm64_kernel<2><<<dim3(128, 2), 256, 0, stream>>>(encb);  // enc
    gemm64_kernel<3><<<dim3(128, 8), 256, 0, stream>>>(acb);   // actor
    critic_kernel<<<512, 256, 0, stream>>>(crb, vw, vb, out + B_*100);
    query_kernel<<<128, 256, 0, stream>>>(emb, abias, out);
}